// Round 1
// baseline (981.981 us; speedup 1.0000x reference)
//
#include <hip/hip_runtime.h>

#define T_STEPS 1000
#define BATCH   64
#define IN_N    300
#define L_N     24
#define A_N     6
#define O_N     200
#define SIGMA   0.1f

// ---------------- K0: transpose w_in (L,IN) -> wT (IN,L) ----------------
__global__ void k0_transpose_win(const float* __restrict__ w_in,
                                 float* __restrict__ wT) {
    int i = blockIdx.x * 256 + threadIdx.x;
    if (i < IN_N * L_N) {
        int k = i / L_N, l = i % L_N;
        wT[i] = w_in[l * IN_N + k];
    }
}

// ---------------- K1: drive = x @ w_in^T + offset + v_rest ----------------
// thread = row (t*B+b); 24 fp32 accumulators; x staged in LDS (transposed read
// pattern is conflict-free via odd pitch 61); weights read via uniform scalar
// loads from the pre-transposed wT (contiguous 96B per k -> s_load merges).
#define K1_ROWS    128
#define K1_THREADS 128
#define KC         60
#define XPITCH     61

__global__ __launch_bounds__(K1_THREADS) void k1_drive(
    const float* __restrict__ x, const float* __restrict__ wT,
    const float* __restrict__ trial_noise, const float* __restrict__ v_rest,
    const float* __restrict__ trial_offset_w, float* __restrict__ drive) {
    __shared__ float xt[K1_ROWS * XPITCH];
    const int tid  = threadIdx.x;
    const int row0 = blockIdx.x * K1_ROWS;

    float acc[L_N];
#pragma unroll
    for (int l = 0; l < L_N; ++l) acc[l] = 0.f;

    const float4* xg = reinterpret_cast<const float4*>(x);
    for (int c = 0; c < IN_N / KC; ++c) {
        // stage 128 rows x 60 floats = 1920 float4
#pragma unroll
        for (int j = 0; j < 15; ++j) {
            int e4 = tid + j * K1_THREADS;
            int r = e4 / 15, kq = e4 % 15;
            float4 v = xg[(row0 + r) * (IN_N / 4) + c * (KC / 4) + kq];
            float* d = &xt[r * XPITCH + kq * 4];
            d[0] = v.x; d[1] = v.y; d[2] = v.z; d[3] = v.w;
        }
        __syncthreads();
        const float* wrow = wT + c * KC * L_N;
#pragma unroll 2
        for (int kk = 0; kk < KC; ++kk) {
            float xv = xt[tid * XPITCH + kk];
#pragma unroll
            for (int l = 0; l < L_N; ++l)
                acc[l] = fmaf(xv, wrow[kk * L_N + l], acc[l]);
        }
        __syncthreads();
    }

    // epilogue: + trial offset + v_rest, write (row, 24) as 6 float4
    const int row = row0 + tid;
    const int b   = row & (BATCH - 1);
    float2 tn = reinterpret_cast<const float2*>(trial_noise)[b];
    float o[L_N];
#pragma unroll
    for (int l = 0; l < L_N; ++l)
        o[l] = acc[l] + tn.x * trial_offset_w[l] + tn.y * trial_offset_w[L_N + l]
             + v_rest[l];
    float4* dg = reinterpret_cast<float4*>(drive + (size_t)row * L_N);
#pragma unroll
    for (int i = 0; i < 6; ++i)
        dg[i] = make_float4(o[4 * i], o[4 * i + 1], o[4 * i + 2], o[4 * i + 3]);
}

// ---------------- K2: sequential scan (1 block per batch, 1 wave) ----------
// lane l holds v[l] and W row; delayed rates broadcast from an 8-slot LDS
// ring (read prefetched 1 step ahead); drive/noise prefetched 8 steps ahead.
__global__ __launch_bounds__(64) void k2_scan(
    const float* __restrict__ drive, const float* __restrict__ mem_noise,
    const float* __restrict__ w_rec, const float* __restrict__ decay_v,
    const float* __restrict__ bias_noise, float* __restrict__ rates) {
    __shared__ __align__(16) float ring[8 * L_N];
    const int tid = threadIdx.x;
    const int b   = blockIdx.x;
    const int l   = (tid < L_N) ? tid : 0;
    const bool act = (tid < L_N);

    float W[L_N];
    const float* wr = w_rec + l * L_N;   // w_rec[0][l][k]
#pragma unroll
    for (int k = 0; k < L_N; ++k) W[k] = wr[k];
    const float dec = decay_v[l];
    const float omd = 1.f - dec;
    const float snl = SIGMA * bias_noise[l];

    for (int i = tid; i < 8 * L_N; i += 64) ring[i] = 0.f;
    __syncthreads();

    float v = 0.f;
    float curD[8], curN[8], nxtD[8], nxtN[8];
#pragma unroll
    for (int d = 0; d < 8; ++d) {
        size_t idx = ((size_t)d * BATCH + b) * L_N + l;
        curD[d] = drive[idx];
        curN[d] = snl * mem_noise[idx];
    }

    float ra[L_N], rb[L_N];
    {   // rates for t=0: slot 3 (zeros)
        const float4* r4 = reinterpret_cast<const float4*>(&ring[3 * L_N]);
#pragma unroll
        for (int q = 0; q < 6; ++q) {
            float4 t = r4[q];
            ra[4 * q] = t.x; ra[4 * q + 1] = t.y;
            ra[4 * q + 2] = t.z; ra[4 * q + 3] = t.w;
        }
    }

    auto step = [&](int t, float (&rc)[L_N], float (&rn)[L_N], float dv, float nv) {
        // prefetch delayed-rate row for step t+1 (slot (t+4)&7, written at t-4)
        const float4* r4 =
            reinterpret_cast<const float4*>(&ring[((t + 4) & 7) * L_N]);
#pragma unroll
        for (int q = 0; q < 6; ++q) {
            float4 tt = r4[q];
            rn[4 * q] = tt.x; rn[4 * q + 1] = tt.y;
            rn[4 * q + 2] = tt.z; rn[4 * q + 3] = tt.w;
        }
        float a0 = 0.f, a1 = 0.f, a2 = 0.f, a3 = 0.f;
#pragma unroll
        for (int k = 0; k < L_N; k += 4) {
            a0 = fmaf(rc[k],     W[k],     a0);
            a1 = fmaf(rc[k + 1], W[k + 1], a1);
            a2 = fmaf(rc[k + 2], W[k + 2], a2);
            a3 = fmaf(rc[k + 3], W[k + 3], a3);
        }
        float irec = (a0 + a1) + (a2 + a3);
        float t1 = dv + irec;
        v = fmaf(dec, v, fmaf(omd, t1, nv));
        float rate = 1.f / (1.f + __expf(-v));
        if (act) {
            ring[(t & 7) * L_N + tid] = rate;
            rates[((size_t)t * BATCH + b) * L_N + tid] = rate;
        }
    };

    for (int tb = 0; tb < T_STEPS; tb += 8) {
#pragma unroll
        for (int d = 0; d < 8; ++d) {
            int t = tb + 8 + d;
            if (t < T_STEPS) {
                size_t idx = ((size_t)t * BATCH + b) * L_N + l;
                nxtD[d] = drive[idx];
                nxtN[d] = snl * mem_noise[idx];
            } else { nxtD[d] = 0.f; nxtN[d] = 0.f; }
        }
        step(tb + 0, ra, rb, curD[0], curN[0]);
        step(tb + 1, rb, ra, curD[1], curN[1]);
        step(tb + 2, ra, rb, curD[2], curN[2]);
        step(tb + 3, rb, ra, curD[3], curN[3]);
        step(tb + 4, ra, rb, curD[4], curN[4]);
        step(tb + 5, rb, ra, curD[5], curN[5]);
        step(tb + 6, ra, rb, curD[6], curN[6]);
        step(tb + 7, rb, ra, curD[7], curN[7]);
#pragma unroll
        for (int d = 0; d < 8; ++d) { curD[d] = nxtD[d]; curN[d] = nxtN[d]; }
    }
}

// ---------------- K3: per-area projection + sigmoid --------------------
// block handles 16 rows x all 1200 outputs; proj_w/proj_b/pop staged in LDS;
// float4 coalesced stores; w registers reused across the 16 rows.
#define K3_ROWS 16
__global__ __launch_bounds__(256) void k3_proj(
    const float* __restrict__ rates, const float* __restrict__ proj_w,
    const float* __restrict__ proj_b, float* __restrict__ out) {
    __shared__ float4 lw[1200];
    __shared__ float4 lb[300];
    __shared__ float4 lp[K3_ROWS * 6];
    const int tid  = threadIdx.x;
    const int row0 = blockIdx.x * K3_ROWS;

    const float4* pw4 = reinterpret_cast<const float4*>(proj_w);
    const float4* pb4 = reinterpret_cast<const float4*>(proj_b);
    const float4* rt4 = reinterpret_cast<const float4*>(rates);
    for (int i = tid; i < 1200; i += 256) lw[i] = pw4[i];
    for (int i = tid; i < 300; i += 256)  lb[i] = pb4[i];
    if (tid < K3_ROWS * 6) lp[tid] = rt4[row0 * 6 + tid];
    __syncthreads();

    float4* out4 = reinterpret_cast<float4*>(out);
    for (int j4 = tid; j4 < 300; j4 += 256) {
        const int a = j4 / 50;           // area of this float4 of outputs
        float4 bb = lb[j4];
        float4 w0 = lw[4 * j4], w1 = lw[4 * j4 + 1];
        float4 w2 = lw[4 * j4 + 2], w3 = lw[4 * j4 + 3];
#pragma unroll 4
        for (int r = 0; r < K3_ROWS; ++r) {
            float4 p = lp[r * 6 + a];
            float o0 = fmaf(w0.x, p.x, fmaf(w0.y, p.y, fmaf(w0.z, p.z, fmaf(w0.w, p.w, bb.x))));
            float o1 = fmaf(w1.x, p.x, fmaf(w1.y, p.y, fmaf(w1.z, p.z, fmaf(w1.w, p.w, bb.y))));
            float o2 = fmaf(w2.x, p.x, fmaf(w2.y, p.y, fmaf(w2.z, p.z, fmaf(w2.w, p.w, bb.z))));
            float o3 = fmaf(w3.x, p.x, fmaf(w3.y, p.y, fmaf(w3.z, p.z, fmaf(w3.w, p.w, bb.w))));
            float4 res;
            res.x = 1.f / (1.f + __expf(-o0));
            res.y = 1.f / (1.f + __expf(-o1));
            res.z = 1.f / (1.f + __expf(-o2));
            res.w = 1.f / (1.f + __expf(-o3));
            out4[(size_t)(row0 + r) * 300 + j4] = res;
        }
    }
}

extern "C" void kernel_launch(void* const* d_in, const int* in_sizes, int n_in,
                              void* d_out, int out_size, void* d_ws, size_t ws_size,
                              hipStream_t stream) {
    const float* x              = (const float*)d_in[0];
    const float* mem_noise      = (const float*)d_in[1];
    const float* trial_noise    = (const float*)d_in[2];
    const float* w_in           = (const float*)d_in[3];
    const float* w_rec          = (const float*)d_in[4];
    const float* v_rest         = (const float*)d_in[5];
    const float* bias_noise     = (const float*)d_in[6];
    const float* trial_offset_w = (const float*)d_in[7];
    const float* decay_v        = (const float*)d_in[8];
    const float* proj_w         = (const float*)d_in[9];
    const float* proj_b         = (const float*)d_in[10];
    float* out = (float*)d_out;

    const size_t TBL = (size_t)T_STEPS * BATCH * L_N;  // 1,536,000 floats
    float* wT    = (float*)d_ws;          // 7200 floats
    float* drive = wT + 7200;             // TBL floats
    float* ratesb = drive + TBL;          // TBL floats
    if (ws_size < (7200 + 2 * TBL) * sizeof(float)) return;  // ws too small

    hipLaunchKernelGGL(k0_transpose_win, dim3(29), dim3(256), 0, stream, w_in, wT);
    hipLaunchKernelGGL(k1_drive, dim3((T_STEPS * BATCH) / K1_ROWS), dim3(K1_THREADS),
                       0, stream, x, wT, trial_noise, v_rest, trial_offset_w, drive);
    hipLaunchKernelGGL(k2_scan, dim3(BATCH), dim3(64), 0, stream,
                       drive, mem_noise, w_rec, decay_v, bias_noise, ratesb);
    hipLaunchKernelGGL(k3_proj, dim3((T_STEPS * BATCH) / K3_ROWS), dim3(256),
                       0, stream, ratesb, proj_w, proj_b, out);
}

// Round 5
// 560.283 us; speedup vs baseline: 1.7527x; 1.7527x over previous
//
#include <hip/hip_runtime.h>

#define T_STEPS 1000
#define BATCH   64
#define IN_N    300
#define L_N     24
#define SIGMA   0.1f
#define RSTR    32            // floats per ring slot (24 + pad)

typedef float f32x4 __attribute__((ext_vector_type(4)));

// ws float layout:
//  [0,7200)      wTs   : w_in^T scaled by (1-dec_l)   [k][l]
//  [7200,7776)   Wss   : w_rec[0] scaled by (1-dec_l) [l][k]
//  [7776,7824)   ow    : trial_offset_w scaled        [2][l]
//  [7824,7848)   c0    : v_rest scaled
//  [7848,7872)   snl   : SIGMA * bias_noise
//  [8192, +TBL)  g     : fused per-step input current (T,B,L)
//  [8192+TBL, +TBL) ratesb : population rates (T,B,L)
#define WS_G_OFF  8192
#define TBL       (T_STEPS * BATCH * L_N)

// ---------------- K0: precompute scaled weights/consts ----------------
__global__ void k0_prep(const float* __restrict__ w_in, const float* __restrict__ w_rec,
                        const float* __restrict__ v_rest, const float* __restrict__ bias_noise,
                        const float* __restrict__ trial_offset_w, const float* __restrict__ decay_v,
                        float* __restrict__ ws) {
    int i = blockIdx.x * 256 + threadIdx.x;
    float* wTs = ws;
    float* Wss = ws + 7200;
    float* ow  = ws + 7776;
    float* c0  = ws + 7824;
    float* snl = ws + 7848;
    if (i < 7200) {
        int k = i / 24, l = i % 24;
        wTs[i] = w_in[l * 300 + k] * (1.f - decay_v[l]);
    } else if (i < 7776) {
        int j = i - 7200; int l = j / 24;
        Wss[j] = w_rec[j] * (1.f - decay_v[l]);
    } else if (i < 7824) {
        int j = i - 7776; int l = j % 24;
        ow[j] = trial_offset_w[j] * (1.f - decay_v[l]);
    } else if (i < 7848) {
        int l = i - 7824;
        c0[l] = v_rest[l] * (1.f - decay_v[l]);
    } else if (i < 7872) {
        int l = i - 7848;
        snl[l] = SIGMA * bias_noise[l];
    }
}

// ---------------- K1: g = (1-dec)*(x@w^T + off + vrest) + sigma*bias*noise ---
#define K1_ROWS    128
#define K1_THREADS 128
#define KC         60
#define XPITCH     61

__global__ __launch_bounds__(K1_THREADS) void k1_drive(
    const float* __restrict__ x, const float* __restrict__ ws,
    const float* __restrict__ trial_noise, const float* __restrict__ mem_noise,
    float* __restrict__ g) {
    __shared__ float xt[K1_ROWS * XPITCH];
    const float* wTs = ws;
    const float* ow  = ws + 7776;
    const float* c0  = ws + 7824;
    const float* snl = ws + 7848;
    const int tid  = threadIdx.x;
    const int row0 = blockIdx.x * K1_ROWS;

    float acc[L_N];
#pragma unroll
    for (int l = 0; l < L_N; ++l) acc[l] = 0.f;

    const float4* xg = reinterpret_cast<const float4*>(x);
    for (int c = 0; c < IN_N / KC; ++c) {
#pragma unroll
        for (int j = 0; j < 15; ++j) {
            int e4 = tid + j * K1_THREADS;
            int r = e4 / 15, kq = e4 % 15;
            float4 v = xg[(row0 + r) * (IN_N / 4) + c * (KC / 4) + kq];
            float* d = &xt[r * XPITCH + kq * 4];
            d[0] = v.x; d[1] = v.y; d[2] = v.z; d[3] = v.w;
        }
        __syncthreads();
        const float* wrow = wTs + c * KC * L_N;
#pragma unroll 2
        for (int kk = 0; kk < KC; ++kk) {
            float xv = xt[tid * XPITCH + kk];
#pragma unroll
            for (int l = 0; l < L_N; ++l)
                acc[l] = fmaf(xv, wrow[kk * L_N + l], acc[l]);
        }
        __syncthreads();
    }

    const int row = row0 + tid;
    const int b   = row & (BATCH - 1);
    float2 tn = reinterpret_cast<const float2*>(trial_noise)[b];
    const float4* nz = reinterpret_cast<const float4*>(mem_noise + (size_t)row * L_N);
    float4 z[6];
#pragma unroll
    for (int q = 0; q < 6; ++q) z[q] = nz[q];
    float zz[L_N];
#pragma unroll
    for (int q = 0; q < 6; ++q) {
        zz[4*q] = z[q].x; zz[4*q+1] = z[q].y; zz[4*q+2] = z[q].z; zz[4*q+3] = z[q].w;
    }
    float o[L_N];
#pragma unroll
    for (int l = 0; l < L_N; ++l)
        o[l] = acc[l] + tn.x * ow[l] + tn.y * ow[L_N + l] + c0[l] + snl[l] * zz[l];
    float4* dg = reinterpret_cast<float4*>(g + (size_t)row * L_N);
#pragma unroll
    for (int i = 0; i < 6; ++i)
        dg[i] = make_float4(o[4*i], o[4*i+1], o[4*i+2], o[4*i+3]);
}

// ---------------- K2: sequential scan, half-wave-split dot ----------------
// v(t) = dec*v(t-1) + g(t) + Ws @ r(t-5);  r = sigmoid(v)
// Ring: 8 slots x 32 floats in LDS, slot (s+3)&7 holds r(s-5) for step s
// (tb multiple of 8 => all slot indices compile-time). Low half lanes handle
// k=0..11, high half k=12..23; combine with one shfl_xor(32). The prefetch
// issued inside step s targets step s+2 (slot (s+5)&7 holds r(s-3), already
// written at step s-3 => no wait hazard beyond lgkmcnt the compiler inserts).
#define K2_STEP(s, C0, C1, C2, CG) do {                                        \
    float p0 = C0.x * W0.x, p1 = C0.y * W0.y, p2 = C0.z * W0.z, p3 = C0.w * W0.w; \
    p0 = fmaf(C1.x, W1.x, p0); p1 = fmaf(C1.y, W1.y, p1);                      \
    p2 = fmaf(C1.z, W1.z, p2); p3 = fmaf(C1.w, W1.w, p3);                      \
    p0 = fmaf(C2.x, W2.x, p0); p1 = fmaf(C2.y, W2.y, p1);                      \
    p2 = fmaf(C2.z, W2.z, p2); p3 = fmaf(C2.w, W2.w, p3);                      \
    { const float4* q_ = reinterpret_cast<const float4*>(                      \
          &ring[(((s) + 5) & 7) * RSTR + h12]);                                \
      C0 = q_[0]; C1 = q_[1]; C2 = q_[2]; }                                    \
    float pa = (p0 + p1) + (p2 + p3);                                          \
    pa += __shfl_xor(pa, 32);                                                  \
    v = fmaf(dec, v, (CG) + pa);                                               \
    float rate_ = 1.f / (1.f + __expf(-v));                                    \
    if (act) {                                                                 \
        ring[((s) & 7) * RSTR + li] = rate_;                                   \
        rp[(tb + (s)) * (BATCH * L_N)] = rate_;                                \
    }                                                                          \
} while (0)

__global__ __launch_bounds__(64) void k2_scan(
    const float* __restrict__ g, const float* __restrict__ ws,
    const float* __restrict__ decay_v, float* __restrict__ rates) {
    __shared__ __align__(16) float ring[8 * RSTR];
    const float* Wss = ws + 7200;
    const int tid  = threadIdx.x;
    const int b    = blockIdx.x;
    const int half = tid >> 5;
    const int li   = tid & 31;
    const int lc   = (li < 24) ? li : 0;
    const bool act = (li < 24) && (half == 0);
    const int h12  = half * 12;

    const float4* wv = reinterpret_cast<const float4*>(Wss + lc * 24 + h12);
    float4 W0 = wv[0], W1 = wv[1], W2 = wv[2];
    const float dec = decay_v[lc];

    ring[tid] = 0.f; ring[tid + 64] = 0.f; ring[tid + 128] = 0.f; ring[tid + 192] = 0.f;
    __syncthreads();

    const float* gp = g + b * L_N + lc;
    float* rp = rates + b * L_N + lc;

    float cg0 = gp[0 * 1536], cg1 = gp[1 * 1536], cg2 = gp[2 * 1536], cg3 = gp[3 * 1536];
    float cg4 = gp[4 * 1536], cg5 = gp[5 * 1536], cg6 = gp[6 * 1536], cg7 = gp[7 * 1536];

    float v = 0.f;
    float4 A0, A1, A2, B0, B1, B2;
    {   // prefetch for steps 0 (slot 3) and 1 (slot 4) -> zeros
        const float4* q = reinterpret_cast<const float4*>(&ring[3 * RSTR + h12]);
        A0 = q[0]; A1 = q[1]; A2 = q[2];
        q = reinterpret_cast<const float4*>(&ring[4 * RSTR + h12]);
        B0 = q[0]; B1 = q[1]; B2 = q[2];
    }

    for (int tb = 0; tb < T_STEPS - 8; tb += 8) {
        const float* gn = gp + (tb + 8) * 1536;
        float n0 = gn[0 * 1536], n1 = gn[1 * 1536], n2 = gn[2 * 1536], n3 = gn[3 * 1536];
        float n4 = gn[4 * 1536], n5 = gn[5 * 1536], n6 = gn[6 * 1536], n7 = gn[7 * 1536];
        K2_STEP(0, A0, A1, A2, cg0);
        K2_STEP(1, B0, B1, B2, cg1);
        K2_STEP(2, A0, A1, A2, cg2);
        K2_STEP(3, B0, B1, B2, cg3);
        K2_STEP(4, A0, A1, A2, cg4);
        K2_STEP(5, B0, B1, B2, cg5);
        K2_STEP(6, A0, A1, A2, cg6);
        K2_STEP(7, B0, B1, B2, cg7);
        cg0 = n0; cg1 = n1; cg2 = n2; cg3 = n3;
        cg4 = n4; cg5 = n5; cg6 = n6; cg7 = n7;
    }
    {
        const int tb = T_STEPS - 8;
        K2_STEP(0, A0, A1, A2, cg0);
        K2_STEP(1, B0, B1, B2, cg1);
        K2_STEP(2, A0, A1, A2, cg2);
        K2_STEP(3, B0, B1, B2, cg3);
        K2_STEP(4, A0, A1, A2, cg4);
        K2_STEP(5, B0, B1, B2, cg5);
        K2_STEP(6, A0, A1, A2, cg6);
        K2_STEP(7, B0, B1, B2, cg7);
    }
}

// ---------------- K3: per-area projection + sigmoid --------------------
#define K3_ROWS 32
__global__ __launch_bounds__(320) void k3_proj(
    const float* __restrict__ rates, const float* __restrict__ proj_w,
    const float* __restrict__ proj_b, float* __restrict__ out) {
    __shared__ float4 lw[1200];
    __shared__ float4 lb[300];
    __shared__ float4 lp[K3_ROWS * 6];
    const int tid  = threadIdx.x;
    const int row0 = blockIdx.x * K3_ROWS;

    const float4* pw4 = reinterpret_cast<const float4*>(proj_w);
    const float4* pb4 = reinterpret_cast<const float4*>(proj_b);
    const float4* rt4 = reinterpret_cast<const float4*>(rates);
    for (int i = tid; i < 1200; i += 320) lw[i] = pw4[i];
    if (tid < 300) lb[tid] = pb4[tid];
    if (tid < K3_ROWS * 6) lp[tid] = rt4[row0 * 6 + tid];
    __syncthreads();

    if (tid < 300) {
        const int a = tid / 50;
        float4 bb = lb[tid];
        float4 w0 = lw[4 * tid], w1 = lw[4 * tid + 1];
        float4 w2 = lw[4 * tid + 2], w3 = lw[4 * tid + 3];
        float4* outp = reinterpret_cast<float4*>(out) + (size_t)row0 * 300 + tid;
#pragma unroll 4
        for (int r = 0; r < K3_ROWS; ++r) {
            float4 p = lp[r * 6 + a];
            float o0 = fmaf(w0.x, p.x, fmaf(w0.y, p.y, fmaf(w0.z, p.z, fmaf(w0.w, p.w, bb.x))));
            float o1 = fmaf(w1.x, p.x, fmaf(w1.y, p.y, fmaf(w1.z, p.z, fmaf(w1.w, p.w, bb.y))));
            float o2 = fmaf(w2.x, p.x, fmaf(w2.y, p.y, fmaf(w2.z, p.z, fmaf(w2.w, p.w, bb.z))));
            float o3 = fmaf(w3.x, p.x, fmaf(w3.y, p.y, fmaf(w3.z, p.z, fmaf(w3.w, p.w, bb.w))));
            f32x4 res;
            res.x = __builtin_amdgcn_rcpf(1.f + __expf(-o0));
            res.y = __builtin_amdgcn_rcpf(1.f + __expf(-o1));
            res.z = __builtin_amdgcn_rcpf(1.f + __expf(-o2));
            res.w = __builtin_amdgcn_rcpf(1.f + __expf(-o3));
            __builtin_nontemporal_store(res, reinterpret_cast<f32x4*>(outp));
            outp += 300;
        }
    }
}

extern "C" void kernel_launch(void* const* d_in, const int* in_sizes, int n_in,
                              void* d_out, int out_size, void* d_ws, size_t ws_size,
                              hipStream_t stream) {
    const float* x              = (const float*)d_in[0];
    const float* mem_noise      = (const float*)d_in[1];
    const float* trial_noise    = (const float*)d_in[2];
    const float* w_in           = (const float*)d_in[3];
    const float* w_rec          = (const float*)d_in[4];
    const float* v_rest         = (const float*)d_in[5];
    const float* bias_noise     = (const float*)d_in[6];
    const float* trial_offset_w = (const float*)d_in[7];
    const float* decay_v        = (const float*)d_in[8];
    const float* proj_w         = (const float*)d_in[9];
    const float* proj_b         = (const float*)d_in[10];
    float* out = (float*)d_out;

    float* ws     = (float*)d_ws;
    float* gbuf   = ws + WS_G_OFF;
    float* ratesb = gbuf + TBL;
    if (ws_size < (size_t)(WS_G_OFF + 2 * TBL) * sizeof(float)) return;

    hipLaunchKernelGGL(k0_prep, dim3(31), dim3(256), 0, stream,
                       w_in, w_rec, v_rest, bias_noise, trial_offset_w, decay_v, ws);
    hipLaunchKernelGGL(k1_drive, dim3((T_STEPS * BATCH) / K1_ROWS), dim3(K1_THREADS),
                       0, stream, x, ws, trial_noise, mem_noise, gbuf);
    hipLaunchKernelGGL(k2_scan, dim3(BATCH), dim3(64), 0, stream,
                       gbuf, ws, decay_v, ratesb);
    hipLaunchKernelGGL(k3_proj, dim3((T_STEPS * BATCH) / K3_ROWS), dim3(320),
                       0, stream, ratesb, proj_w, proj_b, out);
}

// Round 6
// 525.417 us; speedup vs baseline: 1.8690x; 1.0664x over previous
//
#include <hip/hip_runtime.h>

#define T_STEPS 1000
#define BATCH   64
#define IN_N    300
#define L_N     24
#define SIGMA   0.1f

typedef float f32x4 __attribute__((ext_vector_type(4)));

// ws float layout:
//  [0,7200)      wTs   : w_in^T scaled by (1-dec_l)   [k][l]
//  [7200,7776)   Wss   : w_rec[0] scaled by (1-dec_l) [l][k]
//  [7776,7824)   ow    : trial_offset_w scaled        [2][l]
//  [7824,7848)   c0    : v_rest scaled
//  [7848,7872)   snl   : SIGMA * bias_noise
//  [8192, +TBL)  g     : fused per-step input current (T,B,L)
//  [8192+TBL, +TBL) ratesb : population rates (T,B,L)
#define WS_G_OFF  8192
#define TBL       (T_STEPS * BATCH * L_N)

// ---------------- K0: precompute scaled weights/consts ----------------
__global__ void k0_prep(const float* __restrict__ w_in, const float* __restrict__ w_rec,
                        const float* __restrict__ v_rest, const float* __restrict__ bias_noise,
                        const float* __restrict__ trial_offset_w, const float* __restrict__ decay_v,
                        float* __restrict__ ws) {
    int i = blockIdx.x * 256 + threadIdx.x;
    float* wTs = ws;
    float* Wss = ws + 7200;
    float* ow  = ws + 7776;
    float* c0  = ws + 7824;
    float* snl = ws + 7848;
    if (i < 7200) {
        int k = i / 24, l = i % 24;
        wTs[i] = w_in[l * 300 + k] * (1.f - decay_v[l]);
    } else if (i < 7776) {
        int j = i - 7200; int l = j / 24;
        Wss[j] = w_rec[j] * (1.f - decay_v[l]);
    } else if (i < 7824) {
        int j = i - 7776; int l = j % 24;
        ow[j] = trial_offset_w[j] * (1.f - decay_v[l]);
    } else if (i < 7848) {
        int l = i - 7824;
        c0[l] = v_rest[l] * (1.f - decay_v[l]);
    } else if (i < 7872) {
        int l = i - 7848;
        snl[l] = SIGMA * bias_noise[l];
    }
}

// ---------------- K1: g = (1-dec)*(x@w^T + off + vrest) + sigma*bias*noise ---
#define K1_ROWS    128
#define K1_THREADS 128
#define KC         60
#define XPITCH     61

__global__ __launch_bounds__(K1_THREADS) void k1_drive(
    const float* __restrict__ x, const float* __restrict__ ws,
    const float* __restrict__ trial_noise, const float* __restrict__ mem_noise,
    float* __restrict__ g) {
    __shared__ float xt[K1_ROWS * XPITCH];
    const float* wTs = ws;
    const float* ow  = ws + 7776;
    const float* c0  = ws + 7824;
    const float* snl = ws + 7848;
    const int tid  = threadIdx.x;
    const int row0 = blockIdx.x * K1_ROWS;

    float acc[L_N];
#pragma unroll
    for (int l = 0; l < L_N; ++l) acc[l] = 0.f;

    const float4* xg = reinterpret_cast<const float4*>(x);
    for (int c = 0; c < IN_N / KC; ++c) {
#pragma unroll
        for (int j = 0; j < 15; ++j) {
            int e4 = tid + j * K1_THREADS;
            int r = e4 / 15, kq = e4 % 15;
            float4 v = xg[(row0 + r) * (IN_N / 4) + c * (KC / 4) + kq];
            float* d = &xt[r * XPITCH + kq * 4];
            d[0] = v.x; d[1] = v.y; d[2] = v.z; d[3] = v.w;
        }
        __syncthreads();
        const float* wrow = wTs + c * KC * L_N;
#pragma unroll 2
        for (int kk = 0; kk < KC; ++kk) {
            float xv = xt[tid * XPITCH + kk];
#pragma unroll
            for (int l = 0; l < L_N; ++l)
                acc[l] = fmaf(xv, wrow[kk * L_N + l], acc[l]);
        }
        __syncthreads();
    }

    const int row = row0 + tid;
    const int b   = row & (BATCH - 1);
    float2 tn = reinterpret_cast<const float2*>(trial_noise)[b];
    const float4* nz = reinterpret_cast<const float4*>(mem_noise + (size_t)row * L_N);
    float4 z[6];
#pragma unroll
    for (int q = 0; q < 6; ++q) z[q] = nz[q];
    float zz[L_N];
#pragma unroll
    for (int q = 0; q < 6; ++q) {
        zz[4*q] = z[q].x; zz[4*q+1] = z[q].y; zz[4*q+2] = z[q].z; zz[4*q+3] = z[q].w;
    }
    float o[L_N];
#pragma unroll
    for (int l = 0; l < L_N; ++l)
        o[l] = acc[l] + tn.x * ow[l] + tn.y * ow[L_N + l] + c0[l] + snl[l] * zz[l];
    float4* dg = reinterpret_cast<float4*>(g + (size_t)row * L_N);
#pragma unroll
    for (int i = 0; i < 6; ++i)
        dg[i] = make_float4(o[4*i], o[4*i+1], o[4*i+2], o[4*i+3]);
}

// ---------------- K2: 5-step-window scan (exploits N_DELAY=5) ----------------
// v(t) = dec*v(t-1) + g(t) + Ws@r(t-5); r = sigmoid(v).
// Window w handles t = 5w..5w+4. All 5 dot products use r from window w-1
// (exactly the 5-delay), so: 5 dots (ILP-deep), 5 batched shfl_xor(32),
// exact serial 5-fma v-chain, 5 independent sigmoids. Ring: 2 groups x 5
// slots x 32 floats in LDS, double-buffered by window parity; next-window
// reads issue right after this window's writes (same-wave DS ordering), so a
// full window of compute hides LDS latency. Half 0 writes ring, half 1 does
// the global rate stores (issue-load split; v/r replicated in both halves).
#define K2_DOT(A_, B_, C_, PA_) do {                                           \
    float p0 = A_.x * W0.x, p1 = A_.y * W0.y, p2 = A_.z * W0.z, p3 = A_.w * W0.w; \
    p0 = fmaf(B_.x, W1.x, p0); p1 = fmaf(B_.y, W1.y, p1);                      \
    p2 = fmaf(B_.z, W1.z, p2); p3 = fmaf(B_.w, W1.w, p3);                      \
    p0 = fmaf(C_.x, W2.x, p0); p1 = fmaf(C_.y, W2.y, p1);                      \
    p2 = fmaf(C_.z, W2.z, p2); p3 = fmaf(C_.w, W2.w, p3);                      \
    PA_ = (p0 + p1) + (p2 + p3);                                               \
} while (0)

#define K2_SIG(v_) __builtin_amdgcn_rcpf(1.f + __expf(-(v_)))

__global__ __launch_bounds__(64) void k2_scan(
    const float* __restrict__ g, const float* __restrict__ ws,
    const float* __restrict__ decay_v, float* __restrict__ rates) {
    __shared__ __align__(16) float ring[320];   // 2 groups * 5 slots * 32
    const float* Wss = ws + 7200;
    const int tid  = threadIdx.x;
    const int b    = blockIdx.x;
    const int half = tid >> 5;
    const int li   = tid & 31;
    const int lc   = (li < 24) ? li : 0;
    const bool actw = (li < 24) && (half == 0);  // ring writer
    const bool acts = (li < 24) && (half == 1);  // global storer
    const int h12  = half * 12;

    const float4* wv = reinterpret_cast<const float4*>(Wss + lc * 24 + h12);
    float4 W0 = wv[0], W1 = wv[1], W2 = wv[2];
    const float dec = decay_v[lc];

    const float* gp = g + b * L_N + lc;
    float* rp = rates + b * L_N + lc;

    // r(t<0) = 0: start with zeroed fragment registers; ring groups are
    // always written before they are read (group p written by window w=p+2k).
    float4 Z = make_float4(0.f, 0.f, 0.f, 0.f);
    float4 R00 = Z, R01 = Z, R02 = Z, R10 = Z, R11 = Z, R12 = Z;
    float4 R20 = Z, R21 = Z, R22 = Z, R30 = Z, R31 = Z, R32 = Z;
    float4 R40 = Z, R41 = Z, R42 = Z;

    // g prefetch, distance 2 windows
    float ga0 = gp[0], ga1 = gp[1536], ga2 = gp[2*1536], ga3 = gp[3*1536], ga4 = gp[4*1536];
    float gb0 = gp[5*1536], gb1 = gp[6*1536], gb2 = gp[7*1536], gb3 = gp[8*1536], gb4 = gp[9*1536];

    float v = 0.f;

    for (int w = 0; w < 200; ++w) {
        const int t0 = 5 * w;
        // prefetch g for window w+2
        const int tnw = (w < 198) ? (t0 + 10) : 0;
        const float* gnp = gp + tnw * 1536;
        float gc0 = gnp[0], gc1 = gnp[1536], gc2 = gnp[2*1536], gc3 = gnp[3*1536], gc4 = gnp[4*1536];

        // 5 dots over previous window's rates
        float pa0, pa1, pa2, pa3, pa4;
        K2_DOT(R00, R01, R02, pa0);
        K2_DOT(R10, R11, R12, pa1);
        K2_DOT(R20, R21, R22, pa2);
        K2_DOT(R30, R31, R32, pa3);
        K2_DOT(R40, R41, R42, pa4);
        // batched cross-half combine
        pa0 += __shfl_xor(pa0, 32);
        pa1 += __shfl_xor(pa1, 32);
        pa2 += __shfl_xor(pa2, 32);
        pa3 += __shfl_xor(pa3, 32);
        pa4 += __shfl_xor(pa4, 32);

        // exact per-step v-chain (matches reference rounding structure)
        float v0 = fmaf(dec, v,  ga0 + pa0);
        float v1 = fmaf(dec, v0, ga1 + pa1);
        float v2 = fmaf(dec, v1, ga2 + pa2);
        float v3 = fmaf(dec, v2, ga3 + pa3);
        float v4 = fmaf(dec, v3, ga4 + pa4);
        v = v4;

        // 5 independent sigmoids
        float r0 = K2_SIG(v0);
        float r1 = K2_SIG(v1);
        float r2 = K2_SIG(v2);
        float r3 = K2_SIG(v3);
        float r4 = K2_SIG(v4);

        const int grp = (w & 1) * 160;
        if (actw) {
            ring[grp + 0*32 + li] = r0;
            ring[grp + 1*32 + li] = r1;
            ring[grp + 2*32 + li] = r2;
            ring[grp + 3*32 + li] = r3;
            ring[grp + 4*32 + li] = r4;
        }
        // issue next window's fragment reads right after the writes
        // (same-wave DS ops execute in order; broadcast reads, no conflicts)
        {
            const float4* q0 = reinterpret_cast<const float4*>(&ring[grp + 0*32 + h12]);
            R00 = q0[0]; R01 = q0[1]; R02 = q0[2];
            const float4* q1 = reinterpret_cast<const float4*>(&ring[grp + 1*32 + h12]);
            R10 = q1[0]; R11 = q1[1]; R12 = q1[2];
            const float4* q2 = reinterpret_cast<const float4*>(&ring[grp + 2*32 + h12]);
            R20 = q2[0]; R21 = q2[1]; R22 = q2[2];
            const float4* q3 = reinterpret_cast<const float4*>(&ring[grp + 3*32 + h12]);
            R30 = q3[0]; R31 = q3[1]; R32 = q3[2];
            const float4* q4 = reinterpret_cast<const float4*>(&ring[grp + 4*32 + h12]);
            R40 = q4[0]; R41 = q4[1]; R42 = q4[2];
        }
        if (acts) {
            rp[(t0 + 0) * 1536] = r0;
            rp[(t0 + 1) * 1536] = r1;
            rp[(t0 + 2) * 1536] = r2;
            rp[(t0 + 3) * 1536] = r3;
            rp[(t0 + 4) * 1536] = r4;
        }
        ga0 = gb0; ga1 = gb1; ga2 = gb2; ga3 = gb3; ga4 = gb4;
        gb0 = gc0; gb1 = gc1; gb2 = gc2; gb3 = gc3; gb4 = gc4;
    }
}

// ---------------- K3: per-area projection + sigmoid --------------------
#define K3_ROWS 32
__global__ __launch_bounds__(320) void k3_proj(
    const float* __restrict__ rates, const float* __restrict__ proj_w,
    const float* __restrict__ proj_b, float* __restrict__ out) {
    __shared__ float4 lw[1200];
    __shared__ float4 lb[300];
    __shared__ float4 lp[K3_ROWS * 6];
    const int tid  = threadIdx.x;
    const int row0 = blockIdx.x * K3_ROWS;

    const float4* pw4 = reinterpret_cast<const float4*>(proj_w);
    const float4* pb4 = reinterpret_cast<const float4*>(proj_b);
    const float4* rt4 = reinterpret_cast<const float4*>(rates);
    for (int i = tid; i < 1200; i += 320) lw[i] = pw4[i];
    if (tid < 300) lb[tid] = pb4[tid];
    if (tid < K3_ROWS * 6) lp[tid] = rt4[row0 * 6 + tid];
    __syncthreads();

    if (tid < 300) {
        const int a = tid / 50;
        float4 bb = lb[tid];
        float4 w0 = lw[4 * tid], w1 = lw[4 * tid + 1];
        float4 w2 = lw[4 * tid + 2], w3 = lw[4 * tid + 3];
        float4* outp = reinterpret_cast<float4*>(out) + (size_t)row0 * 300 + tid;
#pragma unroll 4
        for (int r = 0; r < K3_ROWS; ++r) {
            float4 p = lp[r * 6 + a];
            float o0 = fmaf(w0.x, p.x, fmaf(w0.y, p.y, fmaf(w0.z, p.z, fmaf(w0.w, p.w, bb.x))));
            float o1 = fmaf(w1.x, p.x, fmaf(w1.y, p.y, fmaf(w1.z, p.z, fmaf(w1.w, p.w, bb.y))));
            float o2 = fmaf(w2.x, p.x, fmaf(w2.y, p.y, fmaf(w2.z, p.z, fmaf(w2.w, p.w, bb.z))));
            float o3 = fmaf(w3.x, p.x, fmaf(w3.y, p.y, fmaf(w3.z, p.z, fmaf(w3.w, p.w, bb.w))));
            f32x4 res;
            res.x = __builtin_amdgcn_rcpf(1.f + __expf(-o0));
            res.y = __builtin_amdgcn_rcpf(1.f + __expf(-o1));
            res.z = __builtin_amdgcn_rcpf(1.f + __expf(-o2));
            res.w = __builtin_amdgcn_rcpf(1.f + __expf(-o3));
            __builtin_nontemporal_store(res, reinterpret_cast<f32x4*>(outp));
            outp += 300;
        }
    }
}

extern "C" void kernel_launch(void* const* d_in, const int* in_sizes, int n_in,
                              void* d_out, int out_size, void* d_ws, size_t ws_size,
                              hipStream_t stream) {
    const float* x              = (const float*)d_in[0];
    const float* mem_noise      = (const float*)d_in[1];
    const float* trial_noise    = (const float*)d_in[2];
    const float* w_in           = (const float*)d_in[3];
    const float* w_rec          = (const float*)d_in[4];
    const float* v_rest         = (const float*)d_in[5];
    const float* bias_noise     = (const float*)d_in[6];
    const float* trial_offset_w = (const float*)d_in[7];
    const float* decay_v        = (const float*)d_in[8];
    const float* proj_w         = (const float*)d_in[9];
    const float* proj_b         = (const float*)d_in[10];
    float* out = (float*)d_out;

    float* ws     = (float*)d_ws;
    float* gbuf   = ws + WS_G_OFF;
    float* ratesb = gbuf + TBL;
    if (ws_size < (size_t)(WS_G_OFF + 2 * TBL) * sizeof(float)) return;

    hipLaunchKernelGGL(k0_prep, dim3(31), dim3(256), 0, stream,
                       w_in, w_rec, v_rest, bias_noise, trial_offset_w, decay_v, ws);
    hipLaunchKernelGGL(k1_drive, dim3((T_STEPS * BATCH) / K1_ROWS), dim3(K1_THREADS),
                       0, stream, x, ws, trial_noise, mem_noise, gbuf);
    hipLaunchKernelGGL(k2_scan, dim3(BATCH), dim3(64), 0, stream,
                       gbuf, ws, decay_v, ratesb);
    hipLaunchKernelGGL(k3_proj, dim3((T_STEPS * BATCH) / K3_ROWS), dim3(320),
                       0, stream, ratesb, proj_w, proj_b, out);
}